// Round 4
// baseline (576.630 us; speedup 1.0000x reference)
//
#include <hip/hip_runtime.h>

#define NG 512
#define HID 64

// ---------------- degree ----------------
__global__ void deg_kernel(const int* __restrict__ dst, int* __restrict__ deg, int E) {
    int e = blockIdx.x * blockDim.x + threadIdx.x;
    if (e < E) atomicAdd(&deg[dst[e]], 1);
}

// ---------------- CSR build ----------------
__global__ void block_sums_kernel(const int* __restrict__ deg, int* __restrict__ bsum, int N) {
    __shared__ int s[256];
    int i = blockIdx.x * 256 + threadIdx.x;
    s[threadIdx.x] = (i < N) ? deg[i] : 0;
    __syncthreads();
    for (int off = 128; off > 0; off >>= 1) {
        if (threadIdx.x < off) s[threadIdx.x] += s[threadIdx.x + off];
        __syncthreads();
    }
    if (threadIdx.x == 0) bsum[blockIdx.x] = s[0];
}

// single-block parallel scan (nb up to any size, chunks of 1024 with carry)
__global__ __launch_bounds__(1024) void scan_bsum_kernel(const int* __restrict__ bsum,
                                                         int* __restrict__ bofs, int nb) {
    __shared__ int s[1024];
    __shared__ int carry;
    if (threadIdx.x == 0) carry = 0;
    __syncthreads();
    for (int base = 0; base < nb; base += 1024) {
        int i = base + threadIdx.x;
        int v = (i < nb) ? bsum[i] : 0;
        s[threadIdx.x] = v;
        __syncthreads();
        for (int off = 1; off < 1024; off <<= 1) {
            int t = (threadIdx.x >= off) ? s[threadIdx.x - off] : 0;
            __syncthreads();
            s[threadIdx.x] += t;
            __syncthreads();
        }
        if (i < nb) bofs[i] = carry + s[threadIdx.x] - v;  // exclusive
        __syncthreads();
        if (threadIdx.x == 1023) carry += s[1023];
        __syncthreads();
    }
}

// in-block scan -> rowptr, plus dinv folded in (reads deg anyway)
__global__ void scan_block_kernel(const int* __restrict__ deg, const int* __restrict__ bofs,
                                  int* __restrict__ rowptr, float* __restrict__ dinv,
                                  int N, int E) {
    __shared__ int tmp[256];
    int i = blockIdx.x * 256 + threadIdx.x;
    int v = (i < N) ? deg[i] : 0;
    tmp[threadIdx.x] = v;
    __syncthreads();
    for (int off = 1; off < 256; off <<= 1) {
        int t = (threadIdx.x >= off) ? tmp[threadIdx.x - off] : 0;
        __syncthreads();
        tmp[threadIdx.x] += t;
        __syncthreads();
    }
    if (i < N) {
        rowptr[i] = bofs[blockIdx.x] + tmp[threadIdx.x] - v;  // exclusive
        dinv[i] = rsqrtf((float)v + 1.0f);
    }
    if (i == 0) rowptr[N] = E;
}

__global__ void bucket_kernel(const int* __restrict__ src, const int* __restrict__ dst,
                              const int* __restrict__ rowptr, int* __restrict__ cur,
                              int* __restrict__ esrc, int E) {
    int e = blockIdx.x * blockDim.x + threadIdx.x;
    if (e >= E) return;
    int d = dst[e];
    int p = rowptr[d] + atomicAdd(&cur[d], 1);
    esrc[p] = src[e];
}

// ---------------- layer 1 fused: h1 = relu( (Ax)@W1 + b1 ), x is [N,2] ----------------
__global__ void layer1_kernel(const float* __restrict__ x, const int* __restrict__ rowptr,
                              const int* __restrict__ esrc, const float* __restrict__ dinv,
                              const float* __restrict__ W1, const float* __restrict__ b1,
                              float* __restrict__ h1, int N) {
    int t = blockIdx.x * blockDim.x + threadIdx.x;
    int node = t >> 6, lane = t & 63;
    if (node >= N) return;
    const float2* x2 = (const float2*)x;
    int k0 = rowptr[node], k1 = rowptr[node + 1];
    float s0 = 0.0f, s1 = 0.0f;
    for (int base = k0; base < k1; base += 64) {
        int cnt = min(64, k1 - base);
        if (lane < cnt) {
            int s = esrc[base + lane];
            float dv = dinv[s];
            float2 xv = x2[s];
            s0 = fmaf(xv.x, dv, s0);
            s1 = fmaf(xv.y, dv, s1);
        }
    }
#pragma unroll
    for (int m = 32; m > 0; m >>= 1) {
        s0 += __shfl_xor(s0, m);
        s1 += __shfl_xor(s1, m);
    }
    float di = dinv[node];
    float2 xn = x2[node];
    float m0 = fmaf(s0, di, xn.x * di * di);
    float m1 = fmaf(s1, di, xn.y * di * di);
    float v = fmaf(m0, W1[lane], fmaf(m1, W1[HID + lane], b1[lane]));
    h1[(size_t)node * HID + lane] = fmaxf(v, 0.0f);
}

// ---------------- layer 2 fully fused ----------------
// per node: agg = dinv[d]*sum h1[s]*dinv[s] + h1[d]*dinv[d]^2   (float4/lane, 4 edges/issue)
// then z = agg@W2 + b2 (W2 in LDS), relu, mean-pool accumulate.
__global__ __launch_bounds__(256, 8) void layer2_fused_kernel(
    const int* __restrict__ rowptr, const int* __restrict__ esrc,
    const float* __restrict__ dinv, const float* __restrict__ h1,
    const float* __restrict__ W2, const float* __restrict__ b2,
    const int* __restrict__ batch, float* __restrict__ gsum, int* __restrict__ gcnt, int N) {
    __shared__ float Ws[HID * HID];  // k-major: Ws[k*64+j]
    {
        float4* Ws4 = (float4*)Ws;
        const float4* W24 = (const float4*)W2;
        for (int t = threadIdx.x; t < HID * HID / 4; t += 256) Ws4[t] = W24[t];
    }
    __syncthreads();
    int lane = threadIdx.x & 63;
    int fl = lane & 15;       // feature-quad
    int eo = lane >> 4;       // edge offset within group of 4
    float bz = b2[lane];
    const float4* h4 = (const float4*)h1;
    int wave = (blockIdx.x * 256 + threadIdx.x) >> 6;
    int nwaves = gridDim.x * 4;
    for (int node = wave; node < N; node += nwaves) {
        int k0 = rowptr[node];
        int k1 = rowptr[node + 1];
        float di = dinv[node];
        float4 self = h4[(size_t)node * 16 + fl];
        float ax = 0.f, ay = 0.f, az = 0.f, aw = 0.f;
        for (int base = k0; base < k1; base += 64) {
            int cnt = min(64, k1 - base);
            int sv = esrc[base + min(lane, cnt - 1)];  // one coalesced chunk load
            float dv = dinv[sv];                       // parallel weight gather
            for (int i0 = 0; i0 < cnt; i0 += 16) {
                int e0 = i0 + eo, e1 = i0 + 4 + eo, e2 = i0 + 8 + eo, e3 = i0 + 12 + eo;
                int s0 = __shfl(sv, e0), s1 = __shfl(sv, e1);
                int s2 = __shfl(sv, e2), s3 = __shfl(sv, e3);
                float w0 = __shfl(dv, e0), w1 = __shfl(dv, e1);
                float w2 = __shfl(dv, e2), w3 = __shfl(dv, e3);
                if (e0 >= cnt) { w0 = 0.f; s0 = node; }
                if (e1 >= cnt) { w1 = 0.f; s1 = node; }
                if (e2 >= cnt) { w2 = 0.f; s2 = node; }
                if (e3 >= cnt) { w3 = 0.f; s3 = node; }
                float4 r0 = h4[(size_t)s0 * 16 + fl];  // 4 independent dwordx4 loads
                float4 r1 = h4[(size_t)s1 * 16 + fl];
                float4 r2 = h4[(size_t)s2 * 16 + fl];
                float4 r3 = h4[(size_t)s3 * 16 + fl];
                ax = fmaf(r0.x, w0, ax); ay = fmaf(r0.y, w0, ay);
                az = fmaf(r0.z, w0, az); aw = fmaf(r0.w, w0, aw);
                ax = fmaf(r1.x, w1, ax); ay = fmaf(r1.y, w1, ay);
                az = fmaf(r1.z, w1, az); aw = fmaf(r1.w, w1, aw);
                ax = fmaf(r2.x, w2, ax); ay = fmaf(r2.y, w2, ay);
                az = fmaf(r2.z, w2, az); aw = fmaf(r2.w, w2, aw);
                ax = fmaf(r3.x, w3, ax); ay = fmaf(r3.y, w3, ay);
                az = fmaf(r3.z, w3, az); aw = fmaf(r3.w, w3, aw);
            }
        }
        // reduce across the 4 eo-groups (fl preserved by xor 16/32)
        ax += __shfl_xor(ax, 16); ay += __shfl_xor(ay, 16);
        az += __shfl_xor(az, 16); aw += __shfl_xor(aw, 16);
        ax += __shfl_xor(ax, 32); ay += __shfl_xor(ay, 32);
        az += __shfl_xor(az, 32); aw += __shfl_xor(aw, 32);
        float dd = di * di;
        float a0 = fmaf(ax, di, self.x * dd);
        float a1 = fmaf(ay, di, self.y * dd);
        float a2 = fmaf(az, di, self.z * dd);
        float a3 = fmaf(aw, di, self.w * dd);
        // matvec: z[lane] = b2 + sum_k agg[k]*W2[k][lane]; agg[q*4+c] lives at lane q, comp c
        float z = bz;
#pragma unroll
        for (int q = 0; q < 16; ++q) {
            z = fmaf(__shfl(a0, q), Ws[(q * 4 + 0) * HID + lane], z);
            z = fmaf(__shfl(a1, q), Ws[(q * 4 + 1) * HID + lane], z);
            z = fmaf(__shfl(a2, q), Ws[(q * 4 + 2) * HID + lane], z);
            z = fmaf(__shfl(a3, q), Ws[(q * 4 + 3) * HID + lane], z);
        }
        z = fmaxf(z, 0.0f);
        int g = batch[node];
        atomicAdd(&gsum[g * HID + lane], z);
        if (lane == 0) atomicAdd(&gcnt[g], 1);
    }
}

// ---------------- head ----------------
__global__ void head_kernel(const float* __restrict__ gsum, const int* __restrict__ gcnt,
                            const float* __restrict__ Wf1, const float* __restrict__ bf1,
                            const float* __restrict__ Wf2, const float* __restrict__ bf2,
                            float* __restrict__ out) {
    __shared__ float gs[HID];
    __shared__ float ts[HID];
    int b = blockIdx.x;
    int j = threadIdx.x;
    float cnt = fmaxf((float)gcnt[b], 1.0f);
    gs[j] = gsum[b * HID + j] / cnt;
    __syncthreads();
    float acc = bf1[j];
#pragma unroll
    for (int k = 0; k < HID; ++k) acc = fmaf(gs[k], Wf1[k * HID + j], acc);
    ts[j] = fmaxf(acc, 0.0f);
    __syncthreads();
    if (j < 4) {
        float o = bf2[j];
#pragma unroll
        for (int k = 0; k < HID; ++k) o = fmaf(ts[k], Wf2[k * 4 + j], o);
        out[b * 4 + j] = o;
    }
}

extern "C" void kernel_launch(void* const* d_in, const int* in_sizes, int n_in,
                              void* d_out, int out_size, void* d_ws, size_t ws_size,
                              hipStream_t stream) {
    const float* x   = (const float*)d_in[0];
    const int*   ei  = (const int*)d_in[1];
    const int*   bat = (const int*)d_in[2];
    const float* W1  = (const float*)d_in[4];
    const float* b1  = (const float*)d_in[5];
    const float* W2  = (const float*)d_in[6];
    const float* b2  = (const float*)d_in[7];
    const float* Wf1 = (const float*)d_in[8];
    const float* bf1 = (const float*)d_in[9];
    const float* Wf2 = (const float*)d_in[10];
    const float* bf2 = (const float*)d_in[11];
    float* out = (float*)d_out;

    int N = in_sizes[2];
    int E = in_sizes[1] / 2;
    const int* src = ei;
    const int* dst = ei + E;
    int nb = (N + 255) / 256;

    char* ws = (char*)d_ws;
    size_t off = 0;
    auto alloc = [&](size_t bytes) {
        char* p = ws + off;
        off = (off + bytes + 255) & ~(size_t)255;
        return p;
    };
    // deg+cur adjacent (one memset); gsum+gcnt adjacent (one memset)
    int*   deg    = (int*)alloc((size_t)N * 4);
    int*   cur    = (int*)alloc((size_t)N * 4);
    float* dinv   = (float*)alloc((size_t)N * 4);
    int*   rowptr = (int*)alloc((size_t)(N + 1) * 4);
    int*   bsum   = (int*)alloc((size_t)nb * 4);
    int*   bofs   = (int*)alloc((size_t)nb * 4);
    int*   esrc   = (int*)alloc((size_t)E * 4);
    float* hbuf   = (float*)alloc((size_t)N * HID * 4);
    float* gsum   = (float*)alloc((size_t)NG * HID * 4);
    int*   gcnt   = (int*)alloc((size_t)NG * 4);

    hipMemsetAsync(deg, 0, (size_t)((char*)cur - (char*)deg) + (size_t)N * 4, stream);
    hipMemsetAsync(gsum, 0, (size_t)((char*)gcnt - (char*)gsum) + (size_t)NG * 4, stream);

    int nh = N * HID;

    // degrees + CSR build (by dst); dinv folded into scan_block
    deg_kernel<<<(E + 255) / 256, 256, 0, stream>>>(dst, deg, E);
    block_sums_kernel<<<nb, 256, 0, stream>>>(deg, bsum, N);
    scan_bsum_kernel<<<1, 1024, 0, stream>>>(bsum, bofs, nb);
    scan_block_kernel<<<nb, 256, 0, stream>>>(deg, bofs, rowptr, dinv, N, E);
    bucket_kernel<<<(E + 255) / 256, 256, 0, stream>>>(src, dst, rowptr, cur, esrc, E);

    // layer 1 fused: hbuf = h1 = relu((Ax)@W1 + b1)
    layer1_kernel<<<(nh + 255) / 256, 256, 0, stream>>>(x, rowptr, esrc, dinv, W1, b1, hbuf, N);

    // layer 2 fully fused: gather h1 -> @W2 -> relu -> pool
    layer2_fused_kernel<<<2048, 256, 0, stream>>>(rowptr, esrc, dinv, hbuf, W2, b2, bat,
                                                  gsum, gcnt, N);

    // head
    head_kernel<<<NG, HID, 0, stream>>>(gsum, gcnt, Wf1, bf1, Wf2, bf2, out);
}

// Round 5
// 401.484 us; speedup vs baseline: 1.4362x; 1.4362x over previous
//
#include <hip/hip_runtime.h>

#define NG 512
#define HID 64

// ---------------- degree ----------------
__global__ void deg_kernel(const int* __restrict__ dst, int* __restrict__ deg, int E) {
    int e = blockIdx.x * blockDim.x + threadIdx.x;
    if (e < E) atomicAdd(&deg[dst[e]], 1);
}

// ---------------- CSR build ----------------
__global__ void block_sums_kernel(const int* __restrict__ deg, int* __restrict__ bsum, int N) {
    __shared__ int s[256];
    int i = blockIdx.x * 256 + threadIdx.x;
    s[threadIdx.x] = (i < N) ? deg[i] : 0;
    __syncthreads();
    for (int off = 128; off > 0; off >>= 1) {
        if (threadIdx.x < off) s[threadIdx.x] += s[threadIdx.x + off];
        __syncthreads();
    }
    if (threadIdx.x == 0) bsum[blockIdx.x] = s[0];
}

__global__ __launch_bounds__(1024) void scan_bsum_kernel(const int* __restrict__ bsum,
                                                         int* __restrict__ bofs, int nb) {
    __shared__ int s[1024];
    __shared__ int carry;
    if (threadIdx.x == 0) carry = 0;
    __syncthreads();
    for (int base = 0; base < nb; base += 1024) {
        int i = base + threadIdx.x;
        int v = (i < nb) ? bsum[i] : 0;
        s[threadIdx.x] = v;
        __syncthreads();
        for (int off = 1; off < 1024; off <<= 1) {
            int t = (threadIdx.x >= off) ? s[threadIdx.x - off] : 0;
            __syncthreads();
            s[threadIdx.x] += t;
            __syncthreads();
        }
        if (i < nb) bofs[i] = carry + s[threadIdx.x] - v;  // exclusive
        __syncthreads();
        if (threadIdx.x == 1023) carry += s[1023];
        __syncthreads();
    }
}

__global__ void scan_block_kernel(const int* __restrict__ deg, const int* __restrict__ bofs,
                                  int* __restrict__ rowptr, float* __restrict__ dinv,
                                  int N, int E) {
    __shared__ int tmp[256];
    int i = blockIdx.x * 256 + threadIdx.x;
    int v = (i < N) ? deg[i] : 0;
    tmp[threadIdx.x] = v;
    __syncthreads();
    for (int off = 1; off < 256; off <<= 1) {
        int t = (threadIdx.x >= off) ? tmp[threadIdx.x - off] : 0;
        __syncthreads();
        tmp[threadIdx.x] += t;
        __syncthreads();
    }
    if (i < N) {
        rowptr[i] = bofs[blockIdx.x] + tmp[threadIdx.x] - v;  // exclusive
        dinv[i] = rsqrtf((float)v + 1.0f);
    }
    if (i == 0) rowptr[N] = E;
}

__global__ void bucket_kernel(const int* __restrict__ src, const int* __restrict__ dst,
                              const int* __restrict__ rowptr, int* __restrict__ cur,
                              int* __restrict__ esrc, int E) {
    int e = blockIdx.x * blockDim.x + threadIdx.x;
    if (e >= E) return;
    int d = dst[e];
    int p = rowptr[d] + atomicAdd(&cur[d], 1);
    esrc[p] = src[e];
}

// ---------------- layer 1 fused: h1 = relu( (Ax)@W1 + b1 ), x is [N,2] ----------------
__global__ void layer1_kernel(const float* __restrict__ x, const int* __restrict__ rowptr,
                              const int* __restrict__ esrc, const float* __restrict__ dinv,
                              const float* __restrict__ W1, const float* __restrict__ b1,
                              float* __restrict__ h1, int N) {
    int t = blockIdx.x * blockDim.x + threadIdx.x;
    int node = t >> 6, lane = t & 63;
    if (node >= N) return;
    const float2* x2 = (const float2*)x;
    int k0 = rowptr[node], k1 = rowptr[node + 1];
    float s0 = 0.0f, s1 = 0.0f;
    for (int base = k0; base < k1; base += 64) {
        int cnt = min(64, k1 - base);
        if (lane < cnt) {
            int s = esrc[base + lane];
            float dv = dinv[s];
            float2 xv = x2[s];
            s0 = fmaf(xv.x, dv, s0);
            s1 = fmaf(xv.y, dv, s1);
        }
    }
#pragma unroll
    for (int m = 32; m > 0; m >>= 1) {
        s0 += __shfl_xor(s0, m);
        s1 += __shfl_xor(s1, m);
    }
    float di = dinv[node];
    float2 xn = x2[node];
    float m0 = fmaf(s0, di, xn.x * di * di);
    float m1 = fmaf(s1, di, xn.y * di * di);
    float v = fmaf(m0, W1[lane], fmaf(m1, W1[HID + lane], b1[lane]));
    h1[(size_t)node * HID + lane] = fmaxf(v, 0.0f);
}

// ---------------- layer 2 fully fused ----------------
// per node: agg = dinv[d]*sum h1[s]*dinv[s] + h1[d]*dinv[d]^2   (float4/lane, 4 edges/issue)
// then z = agg@W2 + b2 (W2 in LDS), relu, mean-pool accumulate.
// __launch_bounds__(256,4): 64-VGPR cap. (256,8)=32 VGPRs SPILLED: R4 showed
// FETCH 859MB/WRITE 137MB of scratch traffic, 334us. ~48 live regs in hot loop.
__global__ __launch_bounds__(256, 4) void layer2_fused_kernel(
    const int* __restrict__ rowptr, const int* __restrict__ esrc,
    const float* __restrict__ dinv, const float* __restrict__ h1,
    const float* __restrict__ W2, const float* __restrict__ b2,
    const int* __restrict__ batch, float* __restrict__ gsum, int* __restrict__ gcnt, int N) {
    __shared__ float Ws[HID * HID];  // k-major: Ws[k*64+j]
    {
        float4* Ws4 = (float4*)Ws;
        const float4* W24 = (const float4*)W2;
        for (int t = threadIdx.x; t < HID * HID / 4; t += 256) Ws4[t] = W24[t];
    }
    __syncthreads();
    int lane = threadIdx.x & 63;
    int fl = lane & 15;       // feature-quad
    int eo = lane >> 4;       // edge offset within group of 4
    float bz = b2[lane];
    const float4* h4 = (const float4*)h1;
    int wave = (blockIdx.x * 256 + threadIdx.x) >> 6;
    int nwaves = gridDim.x * 4;
    for (int node = wave; node < N; node += nwaves) {
        int k0 = rowptr[node];
        int k1 = rowptr[node + 1];
        float di = dinv[node];
        float4 self = h4[(size_t)node * 16 + fl];
        float ax = 0.f, ay = 0.f, az = 0.f, aw = 0.f;
        for (int base = k0; base < k1; base += 64) {
            int cnt = min(64, k1 - base);
            int sv = esrc[base + min(lane, cnt - 1)];  // one coalesced chunk load
            float dv = dinv[sv];                       // parallel weight gather
            for (int i0 = 0; i0 < cnt; i0 += 16) {
                int e0 = i0 + eo, e1 = i0 + 4 + eo, e2 = i0 + 8 + eo, e3 = i0 + 12 + eo;
                int s0 = __shfl(sv, e0), s1 = __shfl(sv, e1);
                int s2 = __shfl(sv, e2), s3 = __shfl(sv, e3);
                float w0 = __shfl(dv, e0), w1 = __shfl(dv, e1);
                float w2 = __shfl(dv, e2), w3 = __shfl(dv, e3);
                if (e0 >= cnt) { w0 = 0.f; s0 = node; }
                if (e1 >= cnt) { w1 = 0.f; s1 = node; }
                if (e2 >= cnt) { w2 = 0.f; s2 = node; }
                if (e3 >= cnt) { w3 = 0.f; s3 = node; }
                float4 r0 = h4[(size_t)s0 * 16 + fl];  // 4 independent dwordx4 loads
                float4 r1 = h4[(size_t)s1 * 16 + fl];
                float4 r2 = h4[(size_t)s2 * 16 + fl];
                float4 r3 = h4[(size_t)s3 * 16 + fl];
                ax = fmaf(r0.x, w0, ax); ay = fmaf(r0.y, w0, ay);
                az = fmaf(r0.z, w0, az); aw = fmaf(r0.w, w0, aw);
                ax = fmaf(r1.x, w1, ax); ay = fmaf(r1.y, w1, ay);
                az = fmaf(r1.z, w1, az); aw = fmaf(r1.w, w1, aw);
                ax = fmaf(r2.x, w2, ax); ay = fmaf(r2.y, w2, ay);
                az = fmaf(r2.z, w2, az); aw = fmaf(r2.w, w2, aw);
                ax = fmaf(r3.x, w3, ax); ay = fmaf(r3.y, w3, ay);
                az = fmaf(r3.z, w3, az); aw = fmaf(r3.w, w3, aw);
            }
        }
        // reduce across the 4 eo-groups (fl preserved by xor 16/32)
        ax += __shfl_xor(ax, 16); ay += __shfl_xor(ay, 16);
        az += __shfl_xor(az, 16); aw += __shfl_xor(aw, 16);
        ax += __shfl_xor(ax, 32); ay += __shfl_xor(ay, 32);
        az += __shfl_xor(az, 32); aw += __shfl_xor(aw, 32);
        float dd = di * di;
        float a0 = fmaf(ax, di, self.x * dd);
        float a1 = fmaf(ay, di, self.y * dd);
        float a2 = fmaf(az, di, self.z * dd);
        float a3 = fmaf(aw, di, self.w * dd);
        // matvec: z[lane] = b2 + sum_k agg[k]*W2[k][lane]; agg[q*4+c] lives at lane q, comp c
        float z = bz;
#pragma unroll
        for (int q = 0; q < 16; ++q) {
            z = fmaf(__shfl(a0, q), Ws[(q * 4 + 0) * HID + lane], z);
            z = fmaf(__shfl(a1, q), Ws[(q * 4 + 1) * HID + lane], z);
            z = fmaf(__shfl(a2, q), Ws[(q * 4 + 2) * HID + lane], z);
            z = fmaf(__shfl(a3, q), Ws[(q * 4 + 3) * HID + lane], z);
        }
        z = fmaxf(z, 0.0f);
        int g = batch[node];
        atomicAdd(&gsum[g * HID + lane], z);
        if (lane == 0) atomicAdd(&gcnt[g], 1);
    }
}

// ---------------- head ----------------
__global__ void head_kernel(const float* __restrict__ gsum, const int* __restrict__ gcnt,
                            const float* __restrict__ Wf1, const float* __restrict__ bf1,
                            const float* __restrict__ Wf2, const float* __restrict__ bf2,
                            float* __restrict__ out) {
    __shared__ float gs[HID];
    __shared__ float ts[HID];
    int b = blockIdx.x;
    int j = threadIdx.x;
    float cnt = fmaxf((float)gcnt[b], 1.0f);
    gs[j] = gsum[b * HID + j] / cnt;
    __syncthreads();
    float acc = bf1[j];
#pragma unroll
    for (int k = 0; k < HID; ++k) acc = fmaf(gs[k], Wf1[k * HID + j], acc);
    ts[j] = fmaxf(acc, 0.0f);
    __syncthreads();
    if (j < 4) {
        float o = bf2[j];
#pragma unroll
        for (int k = 0; k < HID; ++k) o = fmaf(ts[k], Wf2[k * 4 + j], o);
        out[b * 4 + j] = o;
    }
}

extern "C" void kernel_launch(void* const* d_in, const int* in_sizes, int n_in,
                              void* d_out, int out_size, void* d_ws, size_t ws_size,
                              hipStream_t stream) {
    const float* x   = (const float*)d_in[0];
    const int*   ei  = (const int*)d_in[1];
    const int*   bat = (const int*)d_in[2];
    const float* W1  = (const float*)d_in[4];
    const float* b1  = (const float*)d_in[5];
    const float* W2  = (const float*)d_in[6];
    const float* b2  = (const float*)d_in[7];
    const float* Wf1 = (const float*)d_in[8];
    const float* bf1 = (const float*)d_in[9];
    const float* Wf2 = (const float*)d_in[10];
    const float* bf2 = (const float*)d_in[11];
    float* out = (float*)d_out;

    int N = in_sizes[2];
    int E = in_sizes[1] / 2;
    const int* src = ei;
    const int* dst = ei + E;
    int nb = (N + 255) / 256;

    char* ws = (char*)d_ws;
    size_t off = 0;
    auto alloc = [&](size_t bytes) {
        char* p = ws + off;
        off = (off + bytes + 255) & ~(size_t)255;
        return p;
    };
    int*   deg    = (int*)alloc((size_t)N * 4);
    int*   cur    = (int*)alloc((size_t)N * 4);
    float* dinv   = (float*)alloc((size_t)N * 4);
    int*   rowptr = (int*)alloc((size_t)(N + 1) * 4);
    int*   bsum   = (int*)alloc((size_t)nb * 4);
    int*   bofs   = (int*)alloc((size_t)nb * 4);
    int*   esrc   = (int*)alloc((size_t)E * 4);
    float* hbuf   = (float*)alloc((size_t)N * HID * 4);
    float* gsum   = (float*)alloc((size_t)NG * HID * 4);
    int*   gcnt   = (int*)alloc((size_t)NG * 4);

    hipMemsetAsync(deg, 0, (size_t)((char*)cur - (char*)deg) + (size_t)N * 4, stream);
    hipMemsetAsync(gsum, 0, (size_t)((char*)gcnt - (char*)gsum) + (size_t)NG * 4, stream);

    int nh = N * HID;

    deg_kernel<<<(E + 255) / 256, 256, 0, stream>>>(dst, deg, E);
    block_sums_kernel<<<nb, 256, 0, stream>>>(deg, bsum, N);
    scan_bsum_kernel<<<1, 1024, 0, stream>>>(bsum, bofs, nb);
    scan_block_kernel<<<nb, 256, 0, stream>>>(deg, bofs, rowptr, dinv, N, E);
    bucket_kernel<<<(E + 255) / 256, 256, 0, stream>>>(src, dst, rowptr, cur, esrc, E);

    // layer 1 fused: hbuf = h1 = relu((Ax)@W1 + b1)
    layer1_kernel<<<(nh + 255) / 256, 256, 0, stream>>>(x, rowptr, esrc, dinv, W1, b1, hbuf, N);

    // layer 2 fully fused: gather h1 -> @W2 -> relu -> pool
    layer2_fused_kernel<<<4096, 256, 0, stream>>>(rowptr, esrc, dinv, hbuf, W2, b2, bat,
                                                  gsum, gcnt, N);

    head_kernel<<<NG, HID, 0, stream>>>(gsum, gcnt, Wf1, bf1, Wf2, bf2, out);
}